// Round 1
// 504.381 us; speedup vs baseline: 1.0213x; 1.0213x over previous
//
#include <hip/hip_runtime.h>

typedef unsigned short u16;
typedef unsigned int u32;
typedef __bf16 bf16x8 __attribute__((ext_vector_type(8)));
typedef float f32x4 __attribute__((ext_vector_type(4)));

#define EPS 1e-5f
#define INV_NORM 0.088388347648318447f  // 1/sqrt(128)

// d_out element offsets (fp32 elements)
#define OUT_W   0
#define OUT_LOG 2097152
#define OUT_LP  4194304
#define OUT_S   6291456

// d_ws layout (u16 element offsets)
#define WS_BT   0            // Bt: 16384 x 512 bf16
#define WS_LAT  8388608      // latbf: 512 x 128 bf16 (rows 510/511 garbage, unused)
#define WS_A    8454144      // Abf: 4096 x 512 bf16

__device__ __forceinline__ u16 f2b(float f) {
  u32 i = __float_as_uint(f);
  return (u16)((i + 0x7FFFu + ((i >> 16) & 1u)) >> 16);  // RNE
}
__device__ __forceinline__ float wsum(float v) {
#pragma unroll
  for (int off = 32; off > 0; off >>= 1) v += __shfl_down(v, off, 64);
  return v;
}
__device__ __forceinline__ float wmax(float v) {
#pragma unroll
  for (int off = 32; off > 0; off >>= 1) v = fmaxf(v, __shfl_down(v, off, 64));
  return v;
}
// dot of 8 packed bf16 (uint4) against 8 LDS floats
__device__ __forceinline__ float dot8(uint4 u, const float* xp) {
  float s;
  s  = xp[0] * __uint_as_float(u.x << 16);
  s += xp[1] * __uint_as_float(u.x & 0xFFFF0000u);
  s += xp[2] * __uint_as_float(u.y << 16);
  s += xp[3] * __uint_as_float(u.y & 0xFFFF0000u);
  s += xp[4] * __uint_as_float(u.z << 16);
  s += xp[5] * __uint_as_float(u.z & 0xFFFF0000u);
  s += xp[6] * __uint_as_float(u.w << 16);
  s += xp[7] * __uint_as_float(u.w & 0xFFFF0000u);
  return s;
}
// dot of float4 against 4 LDS floats
__device__ __forceinline__ float dot4(float4 u, const float* xp) {
  return xp[0] * u.x + xp[1] * u.y + xp[2] * u.z + xp[3] * u.w;
}

// ---------------- K1: lat = LN(latents @ linear_w^T + linear_b) -> bf16 ----
__global__ __launch_bounds__(128) void k_lat(const float* __restrict__ latents,
                                             const float* __restrict__ lw,
                                             const float* __restrict__ lb,
                                             u16* __restrict__ latbf) {
  int k = blockIdx.x, t = threadIdx.x;
  int wid = t >> 6, lane = t & 63;
  __shared__ float ls[256];
  __shared__ float red[4];
  ls[t] = latents[k * 256 + t];
  ls[t + 128] = latents[k * 256 + 128 + t];
  __syncthreads();
  float v = lb[t];
  const float4* wv = (const float4*)(lw + t * 256);
#pragma unroll
  for (int c = 0; c < 64; c++) v += dot4(wv[c], &ls[c * 4]);
  float s = wsum(v), s2 = wsum(v * v);
  if (lane == 0) { red[wid * 2] = s; red[wid * 2 + 1] = s2; }
  __syncthreads();
  float mean = (red[0] + red[2]) * 0.0078125f;
  float var = (red[1] + red[3]) * 0.0078125f - mean * mean;
  latbf[k * 128 + t] = f2b((v - mean) * rsqrtf(var + EPS));
}

// ---------------- K2: Bt[n][k] = bf16(sprite[k][n]), n=ch*4096+hw ----------
__global__ __launch_bounds__(256) void k_tr(const float* __restrict__ proto,
                                            const float* __restrict__ masks,
                                            u16* __restrict__ Bt) {
  __shared__ u16 tile[64 * 72];  // [k-local][n-local], pad 72
  int t = threadIdx.x;
  int n0 = blockIdx.x * 64;
  int k0 = blockIdx.y * 64;
  int ch = n0 >> 12, hw0 = n0 & 4095;
  int r = t >> 2, c = (t & 3) * 16;
  int kg = k0 + r;
  u16 vals[16];
#pragma unroll
  for (int e = 0; e < 16; e++) vals[e] = 0;
  if (kg < 510) {
    const float* src = (ch < 3) ? (proto + ((size_t)kg * 3 + ch) * 4096 + hw0 + c)
                                : (masks + (size_t)kg * 4096 + hw0 + c);
    const float4* s4 = (const float4*)src;
#pragma unroll
    for (int q = 0; q < 4; q++) {
      float4 u = s4[q];
      vals[q * 4 + 0] = f2b(u.x);
      vals[q * 4 + 1] = f2b(u.y);
      vals[q * 4 + 2] = f2b(u.z);
      vals[q * 4 + 3] = f2b(u.w);
    }
  }
#pragma unroll
  for (int e = 0; e < 16; e++) tile[r * 72 + c + e] = vals[e];
  __syncthreads();
  int nr = t >> 2, kc = (t & 3) * 16;
  u32 u[8];
#pragma unroll
  for (int e = 0; e < 8; e++) {
    u32 lo = tile[(kc + 2 * e) * 72 + nr];
    u32 hi = tile[(kc + 2 * e + 1) * 72 + nr];
    u[e] = lo | (hi << 16);
  }
  u16* dst = Bt + (size_t)(n0 + nr) * 512 + k0 + kc;
  uint4 v0 = {u[0], u[1], u[2], u[3]};
  uint4 v1 = {u[4], u[5], u[6], u[7]};
  *(uint4*)dst = v0;
  *(uint4*)(dst + 8) = v1;
}

// ---------------- K3: per-row anchors+LN+logits+blank+softmax --------------
__global__ __launch_bounds__(128) void k_rows(const float* __restrict__ x,
                                              const float* __restrict__ aw,
                                              const float* __restrict__ ab,
                                              const float* __restrict__ blank,
                                              const u16* __restrict__ latbf,
                                              float* __restrict__ out,
                                              u16* __restrict__ Abf) {
  int n = blockIdx.x;
  int b = n >> 7, p = n & 127;
  int t = threadIdx.x, wid = t >> 6, lane = t & 63;
  __shared__ float xs[128];
  __shared__ float ash[128];
  __shared__ float red[8];
  xs[t] = x[(size_t)b * 16384 + (size_t)t * 128 + p];
  __syncthreads();
  float av = ab[t];
  const float4* awv = (const float4*)(aw + t * 128);
#pragma unroll
  for (int c = 0; c < 32; c++) av += dot4(awv[c], &xs[c * 4]);
  float bv = xs[t] * blank[(p & 1) * 128 + t];
  float s = wsum(av), s2 = wsum(av * av), sb = wsum(bv);
  if (lane == 0) { red[wid * 3] = s; red[wid * 3 + 1] = s2; red[wid * 3 + 2] = sb; }
  __syncthreads();
  float mean = (red[0] + red[3]) * 0.0078125f;
  float var = (red[1] + red[4]) * 0.0078125f - mean * mean;
  float dots = red[2] + red[5];
  float an = (av - mean) * rsqrtf(var + EPS);
  ash[t] = an;
  float bl = dots * INV_NORM;
  __syncthreads();  // ash visible to all
  // thread t owns k = 4t .. 4t+3 (consecutive -> float4 stores)
  const uint4* lv = (const uint4*)(latbf + (size_t)(4 * t) * 128);
  float a0 = 0.f, a1 = 0.f, a2 = 0.f, a3 = 0.f;
#pragma unroll
  for (int c = 0; c < 16; c++) {
    const float* ap = &ash[c * 8];
    a0 += dot8(lv[c], ap);
    a1 += dot8(lv[16 + c], ap);
    a2 += dot8(lv[32 + c], ap);
    a3 += dot8(lv[48 + c], ap);
  }
  float l[4];
  l[0] = a0 * INV_NORM;
  l[1] = a1 * INV_NORM;
  l[2] = (4 * t + 2 < 510) ? a2 * INV_NORM : bl;  // k=510 -> blank
  l[3] = (4 * t + 3 < 510) ? a3 * INV_NORM : bl;  // k=511 -> blank
  float lmax = fmaxf(fmaxf(l[0], l[1]), fmaxf(l[2], l[3]));
  float m = wmax(lmax);
  __syncthreads();  // red reuse
  if (lane == 0) red[wid] = m;
  __syncthreads();
  float M = fmaxf(red[0], red[1]);
  float se = 0.f;
#pragma unroll
  for (int i = 0; i < 4; i++) se += expf(l[i] - M);
  float ssum = wsum(se);
  __syncthreads();  // red reuse
  if (lane == 0) red[wid] = ssum;
  __syncthreads();
  float S = red[0] + red[1];
  float logZ = M + logf(S);
  size_t nb = (size_t)n * 512 + 4 * t;
  size_t lpb = (size_t)OUT_LP + ((size_t)p * 32 + b) * 512 + 4 * t;
  float4 wv4, lg4, lp4;
  u16 ab4[4];
  float* lpv = &lp4.x;
  float* wvv = &wv4.x;
  float* lgv = &lg4.x;
#pragma unroll
  for (int i = 0; i < 4; i++) {
    float lp = l[i] - logZ;
    float w = expf(lp);
    lpv[i] = lp;
    wvv[i] = w;
    lgv[i] = l[i];
    ab4[i] = f2b(w);
  }
  *(float4*)(out + OUT_W + nb) = wv4;
  *(float4*)(out + OUT_LOG + nb) = lg4;
  *(float4*)(out + lpb) = lp4;
  *(uint2*)(Abf + nb) = *(uint2*)ab4;
}

// ---------------- K4: S_out = (weights @ sprite) permuted, bf16 MFMA -------
// v2: 256x256 tile, 8 waves (2M x 4N), BK=64, double-buffered 128 KiB LDS,
// T3-min 2-phase pipeline: STAGE(next) issued BEFORE compute, ONE barrier/kt.
// Same verified XOR k-chunk swizzle (global-side pre-swizzle, linear LDS dest).
// XCD-chunked block swizzle: each XCD chunk keeps full A panel (4 MB) hot in L2.
__global__ __launch_bounds__(512) void k_gemm(const u16* __restrict__ A,
                                              const u16* __restrict__ Bt,
                                              float* __restrict__ out) {
  extern __shared__ u16 lds[];  // [buf=2][ A:256x64 | B:256x64 ] = 131072 B
  int tid = threadIdx.x;
  int wid = tid >> 6, lane = tid & 63;
  int wm = wid >> 2, wn = wid & 3;          // 2 x 4 wave grid; wave tile 128x64
  int quad = lane >> 4, r16 = lane & 15;

  // bijective XCD-chunked swizzle (1024 % 8 == 0); nb-major within chunk so
  // each XCD sees all mb (A fully L2-resident) and 8 contiguous nb panels.
  int wg = ((blockIdx.x & 7) << 7) | ((int)blockIdx.x >> 3);
  int mb = wg & 15, nb = wg >> 4;
  int mBase = mb << 8, nBase = nb << 8;

  // staging: thread t covers row q*64 + (t>>3), k-chunk (t&7), global chunk
  // pre-swizzled so LDS chunk c of row r holds global chunk c ^ (r&7).
  int srow = tid >> 3;                       // 0..63
  int kc8 = ((tid & 7) ^ (srow & 7)) << 3;   // swizzled k-offset (elements)
  int sw = r16 & 7;                          // read-side XOR key
  const size_t aRow = (size_t)(mBase + srow) * 512 + kc8;
  const size_t bRow = (size_t)(nBase + srow) * 512 + kc8;

  f32x4 acc[8][4];
#pragma unroll
  for (int i = 0; i < 8; i++)
#pragma unroll
    for (int j = 0; j < 4; j++) acc[i][j] = (f32x4){0.f, 0.f, 0.f, 0.f};

#define STAGE(buf, kt) do {                                                     \
    _Pragma("unroll")                                                           \
    for (int q = 0; q < 4; q++) {                                               \
      __builtin_amdgcn_global_load_lds(                                         \
          (__attribute__((address_space(1))) void*)(A + aRow +                  \
              (size_t)q * 32768 + (kt) * 64),                                   \
          (__attribute__((address_space(3))) void*)((char*)lds +                \
              (buf) * 65536 + q * 8192 + tid * 16), 16, 0, 0);                  \
      __builtin_amdgcn_global_load_lds(                                         \
          (__attribute__((address_space(1))) void*)(Bt + bRow +                 \
              (size_t)q * 32768 + (kt) * 64),                                   \
          (__attribute__((address_space(3))) void*)((char*)lds +                \
              (buf) * 65536 + 32768 + q * 8192 + tid * 16), 16, 0, 0);          \
    } } while (0)

  STAGE(0, 0);
  __syncthreads();  // drains vmcnt: buf0 resident

  for (int kt = 0; kt < 8; kt++) {
    int cur = kt & 1;
    if (kt < 7) STAGE(cur ^ 1, kt + 1);      // prefetch issued BEFORE compute
    const u16* As_ = lds + cur * 32768;      // element offsets (u16)
    const u16* Bs_ = As_ + 16384;
#pragma unroll
    for (int kk = 0; kk < 2; kk++) {
      int ch = ((quad + 4 * kk) ^ sw) << 3;  // de-swizzled LDS chunk (elements)
      bf16x8 bfr[4];
#pragma unroll
      for (int j = 0; j < 4; j++)
        bfr[j] = *(const bf16x8*)&Bs_[(wn * 64 + j * 16 + r16) * 64 + ch];
#pragma unroll
      for (int i = 0; i < 8; i++) {
        bf16x8 af = *(const bf16x8*)&As_[(wm * 128 + i * 16 + r16) * 64 + ch];
#pragma unroll
        for (int j = 0; j < 4; j++)
          acc[i][j] = __builtin_amdgcn_mfma_f32_16x16x32_bf16(af, bfr[j],
                                                              acc[i][j], 0, 0, 0);
      }
    }
    if (kt < 7) __syncthreads();  // one barrier per kt: drains prefetch vmcnt
                                  // + protects buf[cur] before next overwrite
  }
#undef STAGE

#pragma unroll
  for (int i = 0; i < 8; i++) {
#pragma unroll
    for (int r = 0; r < 4; r++) {
      int mg = mBase + wm * 128 + i * 16 + quad * 4 + r;
      size_t orow = (size_t)((mg & 127) * 32 + (mg >> 7));  // p*32 + b
      float* orp = out + OUT_S + orow * 16384 + nBase + wn * 64 + r16;
#pragma unroll
      for (int j = 0; j < 4; j++) orp[j * 16] = acc[i][j][r];
    }
  }
}

extern "C" void kernel_launch(void* const* d_in, const int* in_sizes, int n_in,
                              void* d_out, int out_size, void* d_ws, size_t ws_size,
                              hipStream_t stream) {
  const float* x = (const float*)d_in[0];
  const float* latents = (const float*)d_in[1];
  const float* blank = (const float*)d_in[2];
  const float* lw = (const float*)d_in[3];
  const float* lb = (const float*)d_in[4];
  const float* aw = (const float*)d_in[5];
  const float* ab = (const float*)d_in[6];
  const float* proto = (const float*)d_in[7];
  const float* masks = (const float*)d_in[8];
  float* out = (float*)d_out;
  u16* ws16 = (u16*)d_ws;
  u16* Bt = ws16 + WS_BT;
  u16* latbf = ws16 + WS_LAT;
  u16* Abf = ws16 + WS_A;

  k_lat<<<510, 128, 0, stream>>>(latents, lw, lb, latbf);
  k_tr<<<dim3(256, 8), 256, 0, stream>>>(proto, masks, Bt);
  k_rows<<<4096, 128, 0, stream>>>(x, aw, ab, blank, latbf, out, Abf);
  k_gemm<<<1024, 512, 131072, stream>>>(Abf, Bt, out);
}

// Round 2
// 498.362 us; speedup vs baseline: 1.0336x; 1.0121x over previous
//
#include <hip/hip_runtime.h>

typedef unsigned short u16;
typedef unsigned int u32;
typedef __bf16 bf16x8 __attribute__((ext_vector_type(8)));
typedef float f32x4 __attribute__((ext_vector_type(4)));

#define EPS 1e-5f
#define INV_NORM 0.088388347648318447f  // 1/sqrt(128)

// d_out element offsets (fp32 elements)
#define OUT_W   0
#define OUT_LOG 2097152
#define OUT_LP  4194304
#define OUT_S   6291456

// d_ws layout (u16 element offsets)
#define WS_BT   0            // Bt: 16384 x 512 bf16
#define WS_LAT  8388608      // latbf: 512 x 128 bf16 (rows 510/511 garbage, unused)
#define WS_A    8454144      // Abf: 4096 x 512 bf16

__device__ __forceinline__ u16 f2b(float f) {
  u32 i = __float_as_uint(f);
  return (u16)((i + 0x7FFFu + ((i >> 16) & 1u)) >> 16);  // RNE
}
__device__ __forceinline__ float wsum(float v) {
#pragma unroll
  for (int off = 32; off > 0; off >>= 1) v += __shfl_down(v, off, 64);
  return v;
}
__device__ __forceinline__ float wmax(float v) {
#pragma unroll
  for (int off = 32; off > 0; off >>= 1) v = fmaxf(v, __shfl_down(v, off, 64));
  return v;
}
// dot of 8 packed bf16 (uint4) against 8 LDS floats
__device__ __forceinline__ float dot8(uint4 u, const float* xp) {
  float s;
  s  = xp[0] * __uint_as_float(u.x << 16);
  s += xp[1] * __uint_as_float(u.x & 0xFFFF0000u);
  s += xp[2] * __uint_as_float(u.y << 16);
  s += xp[3] * __uint_as_float(u.y & 0xFFFF0000u);
  s += xp[4] * __uint_as_float(u.z << 16);
  s += xp[5] * __uint_as_float(u.z & 0xFFFF0000u);
  s += xp[6] * __uint_as_float(u.w << 16);
  s += xp[7] * __uint_as_float(u.w & 0xFFFF0000u);
  return s;
}
// dot of float4 against 4 LDS floats
__device__ __forceinline__ float dot4(float4 u, const float* xp) {
  return xp[0] * u.x + xp[1] * u.y + xp[2] * u.z + xp[3] * u.w;
}

// ---------------- K1: lat = LN(latents @ linear_w^T + linear_b) -> bf16 ----
__global__ __launch_bounds__(128) void k_lat(const float* __restrict__ latents,
                                             const float* __restrict__ lw,
                                             const float* __restrict__ lb,
                                             u16* __restrict__ latbf) {
  int k = blockIdx.x, t = threadIdx.x;
  int wid = t >> 6, lane = t & 63;
  __shared__ float ls[256];
  __shared__ float red[4];
  ls[t] = latents[k * 256 + t];
  ls[t + 128] = latents[k * 256 + 128 + t];
  __syncthreads();
  float v = lb[t];
  const float4* wv = (const float4*)(lw + t * 256);
#pragma unroll
  for (int c = 0; c < 64; c++) v += dot4(wv[c], &ls[c * 4]);
  float s = wsum(v), s2 = wsum(v * v);
  if (lane == 0) { red[wid * 2] = s; red[wid * 2 + 1] = s2; }
  __syncthreads();
  float mean = (red[0] + red[2]) * 0.0078125f;
  float var = (red[1] + red[3]) * 0.0078125f - mean * mean;
  latbf[k * 128 + t] = f2b((v - mean) * rsqrtf(var + EPS));
}

// ---------------- K2: Bt[n][k] = bf16(sprite[k][n]), n=ch*4096+hw ----------
__global__ __launch_bounds__(256) void k_tr(const float* __restrict__ proto,
                                            const float* __restrict__ masks,
                                            u16* __restrict__ Bt) {
  __shared__ u16 tile[64 * 72];  // [k-local][n-local], pad 72
  int t = threadIdx.x;
  int n0 = blockIdx.x * 64;
  int k0 = blockIdx.y * 64;
  int ch = n0 >> 12, hw0 = n0 & 4095;
  int r = t >> 2, c = (t & 3) * 16;
  int kg = k0 + r;
  u16 vals[16];
#pragma unroll
  for (int e = 0; e < 16; e++) vals[e] = 0;
  if (kg < 510) {
    const float* src = (ch < 3) ? (proto + ((size_t)kg * 3 + ch) * 4096 + hw0 + c)
                                : (masks + (size_t)kg * 4096 + hw0 + c);
    const float4* s4 = (const float4*)src;
#pragma unroll
    for (int q = 0; q < 4; q++) {
      float4 u = s4[q];
      vals[q * 4 + 0] = f2b(u.x);
      vals[q * 4 + 1] = f2b(u.y);
      vals[q * 4 + 2] = f2b(u.z);
      vals[q * 4 + 3] = f2b(u.w);
    }
  }
#pragma unroll
  for (int e = 0; e < 16; e++) tile[r * 72 + c + e] = vals[e];
  __syncthreads();
  int nr = t >> 2, kc = (t & 3) * 16;
  u32 u[8];
#pragma unroll
  for (int e = 0; e < 8; e++) {
    u32 lo = tile[(kc + 2 * e) * 72 + nr];
    u32 hi = tile[(kc + 2 * e + 1) * 72 + nr];
    u[e] = lo | (hi << 16);
  }
  u16* dst = Bt + (size_t)(n0 + nr) * 512 + k0 + kc;
  uint4 v0 = {u[0], u[1], u[2], u[3]};
  uint4 v1 = {u[4], u[5], u[6], u[7]};
  *(uint4*)dst = v0;
  *(uint4*)(dst + 8) = v1;
}

// ---------------- K3: per-row anchors+LN+logits+blank+softmax --------------
__global__ __launch_bounds__(128) void k_rows(const float* __restrict__ x,
                                              const float* __restrict__ aw,
                                              const float* __restrict__ ab,
                                              const float* __restrict__ blank,
                                              const u16* __restrict__ latbf,
                                              float* __restrict__ out,
                                              u16* __restrict__ Abf) {
  int n = blockIdx.x;
  int b = n >> 7, p = n & 127;
  int t = threadIdx.x, wid = t >> 6, lane = t & 63;
  __shared__ float xs[128];
  __shared__ float ash[128];
  __shared__ float red[8];
  xs[t] = x[(size_t)b * 16384 + (size_t)t * 128 + p];
  __syncthreads();
  float av = ab[t];
  const float4* awv = (const float4*)(aw + t * 128);
#pragma unroll
  for (int c = 0; c < 32; c++) av += dot4(awv[c], &xs[c * 4]);
  float bv = xs[t] * blank[(p & 1) * 128 + t];
  float s = wsum(av), s2 = wsum(av * av), sb = wsum(bv);
  if (lane == 0) { red[wid * 3] = s; red[wid * 3 + 1] = s2; red[wid * 3 + 2] = sb; }
  __syncthreads();
  float mean = (red[0] + red[3]) * 0.0078125f;
  float var = (red[1] + red[4]) * 0.0078125f - mean * mean;
  float dots = red[2] + red[5];
  float an = (av - mean) * rsqrtf(var + EPS);
  ash[t] = an;
  float bl = dots * INV_NORM;
  __syncthreads();  // ash visible to all
  // thread t owns k = 4t .. 4t+3 (consecutive -> float4 stores)
  const uint4* lv = (const uint4*)(latbf + (size_t)(4 * t) * 128);
  float a0 = 0.f, a1 = 0.f, a2 = 0.f, a3 = 0.f;
#pragma unroll
  for (int c = 0; c < 16; c++) {
    const float* ap = &ash[c * 8];
    a0 += dot8(lv[c], ap);
    a1 += dot8(lv[16 + c], ap);
    a2 += dot8(lv[32 + c], ap);
    a3 += dot8(lv[48 + c], ap);
  }
  float l[4];
  l[0] = a0 * INV_NORM;
  l[1] = a1 * INV_NORM;
  l[2] = (4 * t + 2 < 510) ? a2 * INV_NORM : bl;  // k=510 -> blank
  l[3] = (4 * t + 3 < 510) ? a3 * INV_NORM : bl;  // k=511 -> blank
  float lmax = fmaxf(fmaxf(l[0], l[1]), fmaxf(l[2], l[3]));
  float m = wmax(lmax);
  __syncthreads();  // red reuse
  if (lane == 0) red[wid] = m;
  __syncthreads();
  float M = fmaxf(red[0], red[1]);
  float se = 0.f;
#pragma unroll
  for (int i = 0; i < 4; i++) se += expf(l[i] - M);
  float ssum = wsum(se);
  __syncthreads();  // red reuse
  if (lane == 0) red[wid] = ssum;
  __syncthreads();
  float S = red[0] + red[1];
  float logZ = M + logf(S);
  size_t nb = (size_t)n * 512 + 4 * t;
  size_t lpb = (size_t)OUT_LP + ((size_t)p * 32 + b) * 512 + 4 * t;
  float4 wv4, lg4, lp4;
  u16 ab4[4];
  float* lpv = &lp4.x;
  float* wvv = &wv4.x;
  float* lgv = &lg4.x;
#pragma unroll
  for (int i = 0; i < 4; i++) {
    float lp = l[i] - logZ;
    float w = expf(lp);
    lpv[i] = lp;
    wvv[i] = w;
    lgv[i] = l[i];
    ab4[i] = f2b(w);
  }
  *(float4*)(out + OUT_W + nb) = wv4;
  *(float4*)(out + OUT_LOG + nb) = lg4;
  *(float4*)(out + lpb) = lp4;
  *(uint2*)(Abf + nb) = *(uint2*)ab4;
}

// ---------------- K4: S_out = (weights @ sprite) permuted, bf16 MFMA -------
// v3: 256x256 tile, 8 waves (2M x 4N), BK=64, double-buffered 128 KiB LDS.
// Phase-split pipeline with RAW barriers + counted waits (T3/T4/T5):
//   per kt: {stage half, ds_read kk=0, setprio MFMA x32} x2, then
//   asm vmcnt(0) (own 8 prefetch loads only) + raw s_barrier — no
//   lgkmcnt/expcnt drain, no __syncthreads full-drain.
// Verified XOR k-chunk swizzle (global-side pre-swizzle, linear LDS dest).
// XCD-chunked bijective block swizzle (1024 % 8 == 0).
__global__ __launch_bounds__(512) void k_gemm(const u16* __restrict__ A,
                                              const u16* __restrict__ Bt,
                                              float* __restrict__ out) {
  extern __shared__ u16 lds[];  // [buf=2][ A:256x64 | B:256x64 ] = 131072 B
  int tid = threadIdx.x;
  int wid = tid >> 6, lane = tid & 63;
  int wm = wid >> 2, wn = wid & 3;          // 2 x 4 wave grid; wave tile 128x64
  int quad = lane >> 4, r16 = lane & 15;

  int wg = ((blockIdx.x & 7) << 7) | ((int)blockIdx.x >> 3);
  int mb = wg & 15, nb = wg >> 4;
  int mBase = mb << 8, nBase = nb << 8;

  // staging: thread t covers row q*64 + (t>>3), k-chunk (t&7), global chunk
  // pre-swizzled so LDS chunk c of row r holds global chunk c ^ (r&7).
  int srow = tid >> 3;                       // 0..63
  int kc8 = ((tid & 7) ^ (srow & 7)) << 3;   // swizzled k-offset (elements)
  int sw = r16 & 7;                          // read-side XOR key
  const size_t aRow = (size_t)(mBase + srow) * 512 + kc8;
  const size_t bRow = (size_t)(nBase + srow) * 512 + kc8;

  f32x4 acc[8][4];
#pragma unroll
  for (int i = 0; i < 8; i++)
#pragma unroll
    for (int j = 0; j < 4; j++) acc[i][j] = (f32x4){0.f, 0.f, 0.f, 0.f};

  // one A + one B 16B load for quarter q of K-tile kt into buffer buf
#define STG(buf, kt, q)                                                         \
  do {                                                                          \
    __builtin_amdgcn_global_load_lds(                                           \
        (__attribute__((address_space(1))) void*)(A + aRow +                    \
            (size_t)(q) * 32768 + (kt) * 64),                                   \
        (__attribute__((address_space(3))) void*)((char*)lds +                  \
            (buf) * 65536 + (q) * 8192 + tid * 16), 16, 0, 0);                  \
    __builtin_amdgcn_global_load_lds(                                           \
        (__attribute__((address_space(1))) void*)(Bt + bRow +                   \
            (size_t)(q) * 32768 + (kt) * 64),                                   \
        (__attribute__((address_space(3))) void*)((char*)lds +                  \
            (buf) * 65536 + 32768 + (q) * 8192 + tid * 16), 16, 0, 0);          \
  } while (0)

  // prologue: stage K-tile 0 into buf0, full drain once
  STG(0, 0, 0); STG(0, 0, 1); STG(0, 0, 2); STG(0, 0, 3);
  asm volatile("s_waitcnt vmcnt(0)" ::: "memory");
  __builtin_amdgcn_s_barrier();

#pragma unroll
  for (int kt = 0; kt < 8; ++kt) {
    const int cur = kt & 1;
    const u16* As_ = lds + cur * 32768;      // element offsets (u16)
    const u16* Bs_ = As_ + 16384;
#pragma unroll
    for (int kk = 0; kk < 2; ++kk) {
      // issue half of next tile's staging under this phase's compute
      if (kt < 7) { STG(cur ^ 1, kt + 1, 2 * kk); STG(cur ^ 1, kt + 1, 2 * kk + 1); }
      int ch = ((quad + 4 * kk) ^ sw) << 3;  // de-swizzled LDS chunk (elements)
      bf16x8 bfr[4], af[8];
#pragma unroll
      for (int j = 0; j < 4; j++)
        bfr[j] = *(const bf16x8*)&Bs_[(wn * 64 + j * 16 + r16) * 64 + ch];
#pragma unroll
      for (int i = 0; i < 8; i++)
        af[i] = *(const bf16x8*)&As_[(wm * 128 + i * 16 + r16) * 64 + ch];
      __builtin_amdgcn_s_setprio(1);
#pragma unroll
      for (int i = 0; i < 8; i++)
#pragma unroll
        for (int j = 0; j < 4; j++)
          acc[i][j] = __builtin_amdgcn_mfma_f32_16x16x32_bf16(af[i], bfr[j],
                                                              acc[i][j], 0, 0, 0);
      __builtin_amdgcn_s_setprio(0);
    }
    if (kt < 7) {
      // own 8 prefetch loads are the only outstanding VMEM: counted == 0 here,
      // but NO lgkm/exp drain and no compiler full-drain. Every wave waits its
      // own loads, then barriers -> all waves' staged bytes visible (m152-safe).
      asm volatile("s_waitcnt vmcnt(0)" ::: "memory");
      __builtin_amdgcn_s_barrier();
    }
  }
#undef STG

#pragma unroll
  for (int i = 0; i < 8; i++) {
#pragma unroll
    for (int r = 0; r < 4; r++) {
      int mg = mBase + wm * 128 + i * 16 + quad * 4 + r;
      size_t orow = (size_t)((mg & 127) * 32 + (mg >> 7));  // p*32 + b
      float* orp = out + OUT_S + orow * 16384 + nBase + wn * 64 + r16;
#pragma unroll
      for (int j = 0; j < 4; j++) orp[j * 16] = acc[i][j][r];
    }
  }
}

extern "C" void kernel_launch(void* const* d_in, const int* in_sizes, int n_in,
                              void* d_out, int out_size, void* d_ws, size_t ws_size,
                              hipStream_t stream) {
  const float* x = (const float*)d_in[0];
  const float* latents = (const float*)d_in[1];
  const float* blank = (const float*)d_in[2];
  const float* lw = (const float*)d_in[3];
  const float* lb = (const float*)d_in[4];
  const float* aw = (const float*)d_in[5];
  const float* ab = (const float*)d_in[6];
  const float* proto = (const float*)d_in[7];
  const float* masks = (const float*)d_in[8];
  float* out = (float*)d_out;
  u16* ws16 = (u16*)d_ws;
  u16* Bt = ws16 + WS_BT;
  u16* latbf = ws16 + WS_LAT;
  u16* Abf = ws16 + WS_A;

  k_lat<<<510, 128, 0, stream>>>(latents, lw, lb, latbf);
  k_tr<<<dim3(256, 8), 256, 0, stream>>>(proto, masks, Bt);
  k_rows<<<4096, 128, 0, stream>>>(x, aw, ab, blank, latbf, out, Abf);
  k_gemm<<<1024, 512, 131072, stream>>>(Abf, Bt, out);
}